// Round 11
// baseline (551.587 us; speedup 1.0000x reference)
//
#include <hip/hip_runtime.h>
#include <hip/hip_bf16.h>
#include <cstdint>
#include <cstddef>

#define N_NODES 50000
#define N_EDGES 600000
#define DF 128
#define N_ETYPES 4
#define N_STEPS 5
#define SCAN_NB 196        // ceil(50000/256)
#define GRU_TILES 3125     // 50000/16 exact
#define GRU_BLOCKS 256     // 1 block/CU
#define LIN_BLOCKS 256     // k_lin (step-0 only)
#define TSTRIDE 136        // k_lin LDS out-tile row stride (f16)
#define XPSTR 17           // Xp row stride (f32): <=2-way banks
#define OSTR 40            // Ow row stride (f16): 80B rows, 16B-aligned chunks
#define FILL_CHUNKS 2344   // ceil(600000/256)
#define FILL_RANGE (N_NODES / 8)   // 6250 nodes per XCD range

typedef _Float16 f16x8 __attribute__((ext_vector_type(8)));
typedef _Float16 f16x4 __attribute__((ext_vector_type(4)));
typedef float f32x4 __attribute__((ext_vector_type(4)));

__device__ __forceinline__ float sigmoid_fast(float x) {
    return 1.0f / (1.0f + __expf(-x));
}
__device__ __forceinline__ float tanh_fast(float x) {
    return 1.0f - 2.0f / (__expf(2.0f * x) + 1.0f);
}

// ---------------- setup kernels (once per launch) ----------------

__global__ __launch_bounds__(256) void k_setup(
    const float* __restrict__ Wl, const float* __restrict__ wih,
    const float* __restrict__ whh, const float* __restrict__ h,
    const int* __restrict__ dst,
    _Float16* __restrict__ Wl_h, _Float16* __restrict__ Bc,
    _Float16* __restrict__ hh, int* __restrict__ deg) {
    int i = blockIdx.x * 256 + threadIdx.x;
    if (i < N_ETYPES * DF * DF * 3 / 2) {            // 98304: Bc (+ Wl_h for i<65536)
        if (i < N_ETYPES * DF * DF) Wl_h[i] = (_Float16)Wl[i];
        int row = i >> 8;                            // 0..383 = g*128 + c
        int k = i & 255;
        float v = (k < 128) ? wih[row * 128 + k] : whh[row * 128 + (k - 128)];
        Bc[i] = (_Float16)v;
    }
    if (i < N_NODES * DF / 4) {                      // 1.6M float4 chunks
        float4 v = ((const float4*)h)[i];
        f16x4 o;
        o.x = (_Float16)v.x; o.y = (_Float16)v.y;
        o.z = (_Float16)v.z; o.w = (_Float16)v.w;
        ((f16x4*)hh)[i] = o;
    }
    if (i < N_EDGES) atomicAdd(&deg[dst[i]], 1);
}

__global__ __launch_bounds__(256) void k_part(
    const int* __restrict__ deg, int* __restrict__ part, int N) {
    __shared__ int s[256];
    int t = threadIdx.x, i = blockIdx.x * 256 + t;
    s[t] = (i < N) ? deg[i] : 0;
    __syncthreads();
    for (int off = 128; off > 0; off >>= 1) {
        if (t < off) s[t] += s[t + off];
        __syncthreads();
    }
    if (t == 0) part[blockIdx.x] = s[0];
}

__global__ __launch_bounds__(256) void k_scan1(int* __restrict__ part, int nb) {
    __shared__ int s[256];
    int t = threadIdx.x;
    int v = (t < nb) ? part[t] : 0;
    s[t] = v;
    __syncthreads();
    for (int off = 1; off < 256; off <<= 1) {
        int u = (t >= off) ? s[t - off] : 0;
        __syncthreads();
        s[t] += u;
        __syncthreads();
    }
    if (t < nb) part[t] = s[t] - v;
}

__global__ __launch_bounds__(256) void k_row(
    const int* __restrict__ deg, const int* __restrict__ part,
    int* __restrict__ row_start, int* __restrict__ cursor, int N) {
    __shared__ int s[256];
    int t = threadIdx.x, i = blockIdx.x * 256 + t;
    int d = (i < N) ? deg[i] : 0;
    s[t] = d;
    __syncthreads();
    for (int off = 1; off < 256; off <<= 1) {
        int u = (t >= off) ? s[t - off] : 0;
        __syncthreads();
        s[t] += u;
        __syncthreads();
    }
    int rs = part[blockIdx.x] + s[t] - d;
    if (i < N) {
        row_start[i] = rs;
        cursor[i] = rs;
        if (i == N - 1) row_start[N] = rs + d;
    }
}

// XCD-partitioned CSR scatter (R5 verified win).
__global__ __launch_bounds__(256) void k_fill(
    const int* __restrict__ src, const int* __restrict__ dst,
    const int* __restrict__ ety, int* __restrict__ cursor,
    int* __restrict__ csr, int E) {
    const int range = blockIdx.x & 7;
    const int chunk = blockIdx.x >> 3;
    const int e = chunk * 256 + threadIdx.x;
    const int lo = range * FILL_RANGE;
    const int hi = lo + FILL_RANGE;
    if (e < E) {
        int d = dst[e];
        if (d >= lo && d < hi) {
            int slot = atomicAdd(&cursor[d], 1);
            csr[slot] = src[e] | ((ety[e] - 1) << 16);   // src < 65536, et in 0..3
        }
    }
}

// ---------------- per-step kernels ----------------

// t_0 only (R4 verified)
__global__ __launch_bounds__(1024) void k_lin(
    const _Float16* __restrict__ hh, const _Float16* __restrict__ Wl,
    const float* __restrict__ b_lin, _Float16* __restrict__ t_out, int N) {
    __shared__ _Float16 O[2][N_ETYPES * 16 * TSTRIDE];
    __shared__ __align__(16) char Ast[4][4096];
    const int wave = threadIdx.x >> 6, lane = threadIdx.x & 63;
    const int col16 = lane & 15, quad = lane >> 4;
    const int g = wave >> 2;
    const int s = wave & 3;

    f16x8 b[2][4];
#pragma unroll
    for (int ct = 0; ct < 2; ct++) {
        const _Float16* bp = Wl + (size_t)g * DF * DF
                           + (size_t)(s * 32 + ct * 16 + col16) * DF + quad * 8;
#pragma unroll
        for (int kt = 0; kt < 4; kt++) b[ct][kt] = *(const f16x8*)(bp + kt * 32);
    }
    const float bias0 = b_lin[g * DF + s * 32 + col16];
    const float bias1 = b_lin[g * DF + s * 32 + 16 + col16];

    const int olocal = (wave & 3) * 1024 + lane * 16;
    const int oswl = olocal ^ (((olocal >> 8) & 7) << 4);
    const int abase = col16 * 256 + quad * 16;
    const int axor = (col16 & 7) << 4;

    auto STAGE = [&](int iter) {
        if (wave < 4) {
            int tt = blockIdx.x + iter * LIN_BLOCKS;
            if (tt >= GRU_TILES) tt = GRU_TILES - 1;
            const char* gp = (const char*)hh + (size_t)tt * 4096 + oswl;
            char* lp = &Ast[iter & 3][(wave & 3) * 1024];
            __builtin_amdgcn_global_load_lds(
                (const __attribute__((address_space(1))) void*)gp,
                (__attribute__((address_space(3))) void*)lp, 16, 0, 0);
        }
    };

    const int ek = threadIdx.x >> 8;
    const int erow = (threadIdx.x & 255) >> 4;
    const int ec8 = threadIdx.x & 15;

    STAGE(0);
    STAGE(1);
    asm volatile("s_waitcnt vmcnt(1)" ::: "memory");
    __builtin_amdgcn_s_barrier();
    __builtin_amdgcn_sched_barrier(0);

    int it = 0;
    for (int tile = blockIdx.x; tile < GRU_TILES; tile += LIN_BLOCKS, ++it) {
        const int r0 = tile * 16;
        STAGE(it + 2);

        const char* As = (const char*)Ast[it & 3];
        _Float16* Ob = O[it & 1];

        f16x8 A[4];
#pragma unroll
        for (int kt = 0; kt < 4; kt++) {
            int off = (abase + kt * 64) ^ axor;
            A[kt] = *(const f16x8*)(As + off);
        }

        f32x4 acc0 = {0.f, 0.f, 0.f, 0.f}, acc1 = {0.f, 0.f, 0.f, 0.f};
#pragma unroll
        for (int kt = 0; kt < 4; kt++) {
            acc0 = __builtin_amdgcn_mfma_f32_16x16x32_f16(A[kt], b[0][kt], acc0, 0, 0, 0);
            acc1 = __builtin_amdgcn_mfma_f32_16x16x32_f16(A[kt], b[1][kt], acc1, 0, 0, 0);
        }

        _Float16* Og = Ob + g * (16 * TSTRIDE);
#pragma unroll
        for (int i = 0; i < 4; i++) {
            Og[(quad * 4 + i) * TSTRIDE + s * 32 + col16] = (_Float16)(acc0[i] + bias0);
            Og[(quad * 4 + i) * TSTRIDE + s * 32 + 16 + col16] = (_Float16)(acc1[i] + bias1);
        }

        asm volatile("s_waitcnt vmcnt(1) lgkmcnt(0)" ::: "memory");
        __builtin_amdgcn_s_barrier();
        __builtin_amdgcn_sched_barrier(0);

        f16x8 v = *(const f16x8*)&Ob[ek * (16 * TSTRIDE) + erow * TSTRIDE + ec8 * 8];
        *(f16x8*)(t_out + ((size_t)ek * N + (r0 + erow)) * DF + ec8 * 8) = v;
    }
    asm volatile("s_waitcnt vmcnt(0)" ::: "memory");
}

// a[n][:] = sum over incoming edges of t[et][src][:] (verified; at the random
// 256B-gather delivered-bytes wall ~4TB/s from L3)
__global__ __launch_bounds__(256) void k_agg(
    const _Float16* __restrict__ t, const int* __restrict__ row_start,
    const int* __restrict__ csr, _Float16* __restrict__ ah, int N) {
    const int wave = threadIdx.x >> 6, lane = threadIdx.x & 63;
    const int g4 = lane >> 4;
    const int c8 = lane & 15;
    const int n = blockIdx.x * 4 + wave;
    const int beg = row_start[n], end = row_start[n + 1];
    float acc[8] = {0.f, 0.f, 0.f, 0.f, 0.f, 0.f, 0.f, 0.f};
    for (int e = beg; e < end; e += 16) {
        int i0 = e + g4, i1 = e + 4 + g4, i2 = e + 8 + g4, i3 = e + 12 + g4;
        float m0 = (i0 < end) ? 1.0f : 0.0f;
        float m1 = (i1 < end) ? 1.0f : 0.0f;
        float m2 = (i2 < end) ? 1.0f : 0.0f;
        float m3 = (i3 < end) ? 1.0f : 0.0f;
        int j0 = (i0 < end) ? i0 : end - 1;
        int j1 = (i1 < end) ? i1 : end - 1;
        int j2 = (i2 < end) ? i2 : end - 1;
        int j3 = (i3 < end) ? i3 : end - 1;
        int p0 = csr[j0], p1 = csr[j1], p2 = csr[j2], p3 = csr[j3];
        f16x8 x0 = *(const f16x8*)(t + ((((size_t)(p0 >> 16)) * N + (p0 & 0xFFFF)) << 7) + c8 * 8);
        f16x8 x1 = *(const f16x8*)(t + ((((size_t)(p1 >> 16)) * N + (p1 & 0xFFFF)) << 7) + c8 * 8);
        f16x8 x2 = *(const f16x8*)(t + ((((size_t)(p2 >> 16)) * N + (p2 & 0xFFFF)) << 7) + c8 * 8);
        f16x8 x3 = *(const f16x8*)(t + ((((size_t)(p3 >> 16)) * N + (p3 & 0xFFFF)) << 7) + c8 * 8);
#pragma unroll
        for (int j = 0; j < 8; j++) acc[j] += m0 * (float)x0[j];
#pragma unroll
        for (int j = 0; j < 8; j++) acc[j] += m1 * (float)x1[j];
#pragma unroll
        for (int j = 0; j < 8; j++) acc[j] += m2 * (float)x2[j];
#pragma unroll
        for (int j = 0; j < 8; j++) acc[j] += m3 * (float)x3[j];
    }
#pragma unroll
    for (int j = 0; j < 8; j++) {
        acc[j] += __shfl_xor(acc[j], 32, 64);
        acc[j] += __shfl_xor(acc[j], 16, 64);
    }
    if (lane < 16) {
        f16x8 o;
#pragma unroll
        for (int j = 0; j < 8; j++) o[j] = (_Float16)acc[j];
        *(f16x8*)(ah + ((size_t)n << 7) + c8 * 8) = o;
    }
}

// FUSED GRU + next-step linear, 16-wave SPLIT-K (R11). Mechanism: R8-R10 were
// TLP-starved (8 waves/CU = 2/SIMD, Occupancy 18%) because persistent weights
// (~160 regs) forced 1 small block/CU. Split K across wave pairs: wave =
// (cg in [0,8): 16-col group, kh in {0,1}: K-half). Persistent regs/wave drop
// to 80 (gru br/bz/bn 12 frags over K=128 + lin wl 8 frags) -> fits the
// 128-VGPR cap of 4 waves/SIMD -> 16 waves resident (2x TLP), 12+8 MFMAs/wave
// (half). kh0's partials (ar, az, i_n) combine via LDS Xp; after barrier B1
// kh1 does the in-register epilogue + Hn write WHILE kh0 does the previous
// tile's global stores (overlapped, not serial). lin after B2 (all 16 waves,
// single-buffered Ow: stores read pre-B2, lin writes post-B2). Bottom wait =
// vmcnt(4): per kh0 wave the last 4 VMEM ops are [stage(it+2), st x3], so
// <=4 outstanding guarantees stage(it+1) + earlier stores complete (in-order).
__global__ __launch_bounds__(1024) void k_grulin(
    const _Float16* __restrict__ ah, const _Float16* __restrict__ hh,
    const _Float16* __restrict__ Bc, const float* __restrict__ b_ih,
    const float* __restrict__ b_hh, const _Float16* __restrict__ Wl,
    const float* __restrict__ b_lin, _Float16* __restrict__ hh_next,
    _Float16* __restrict__ t_out, float* __restrict__ out_f32, int N) {
    __shared__ __align__(16) char Ast[4][8192];      // A-tile ring: [slot][ah 4KB | hh 4KB]
    __shared__ __align__(16) char Hn[2][4096];       // h_next tile, XOR-swizzled, dbuf
    __shared__ float Xp[8][3][16 * XPSTR];           // K-half partials: [cg][gate r,z,i_n]
    __shared__ _Float16 Ow[16][16 * OSTR];           // per-wave t transpose (single buf)
    const int wave = threadIdx.x >> 6, lane = threadIdx.x & 63;
    const int col16 = lane & 15, quad = lane >> 4;
    const int cg = wave & 7, kh = wave >> 3;
    const int c = cg * 16 + col16;                   // gru output col 0..127

    // gru persistent B frags, own K-half only: 12 frags = 48 VGPR
    f16x8 br[4], bz[4], bn[4];
    {
        const _Float16* Br = Bc + ((size_t)c << 8) + kh * 128;
        const _Float16* Bz = Bc + ((size_t)(128 + c) << 8) + kh * 128;
        const _Float16* Bn = Bc + ((size_t)(256 + c) << 8) + kh * 128;
#pragma unroll
        for (int kt = 0; kt < 4; kt++) {
            br[kt] = *(const f16x8*)(Br + kt * 32 + quad * 8);
            bz[kt] = *(const f16x8*)(Bz + kt * 32 + quad * 8);
            bn[kt] = *(const f16x8*)(Bn + kt * 32 + quad * 8);
        }
    }
    const float bir = b_ih[c] + b_hh[c];
    const float biz = b_ih[128 + c] + b_hh[128 + c];
    const float bin_ = b_ih[256 + c];
    const float bhn_ = b_hh[256 + c];

    // lin persistent W frags: wave -> (etype = wave&3, col-quarter = wave>>2)
    const int let = wave & 3;
    const int cq32 = (wave >> 2) * 32;
    f16x8 wl[2][4];
    float blv[2];
#pragma unroll
    for (int ct = 0; ct < 2; ct++) {
        const _Float16* wp = Wl + (size_t)let * DF * DF
                           + (size_t)(cq32 + ct * 16 + col16) * DF + quad * 8;
#pragma unroll
        for (int kt = 0; kt < 4; kt++) wl[ct][kt] = *(const f16x8*)(wp + kt * 32);
        blv[ct] = b_lin[let * DF + cq32 + ct * 16 + col16];
    }

    const int olocal = (wave & 3) * 1024 + lane * 16;
    const int oswl = olocal ^ (((olocal >> 8) & 7) << 4);
    const char* sbase = (wave < 4) ? (const char*)ah : (const char*)hh;
    const int abase = col16 * 256 + quad * 16;
    const int axor = (col16 & 7) << 4;

    // prev-tile store lanes (kh0 threads = tid < 512)
    const int hrow = threadIdx.x >> 5, hch = threadIdx.x & 31;  // h_next: 16x32 f16x4

    auto STAGE = [&](int tidx) {
        if (wave < 8) {
            int tt = blockIdx.x + tidx * GRU_BLOCKS;
            if (tt >= GRU_TILES) tt = GRU_TILES - 1; // clamp keeps vmcnt accounting uniform
            const char* gp = sbase + (size_t)tt * 4096 + oswl;
            char* lp = &Ast[tidx & 3][wave * 1024];
            __builtin_amdgcn_global_load_lds(
                (const __attribute__((address_space(1))) void*)gp,
                (__attribute__((address_space(3))) void*)lp, 16, 0, 0);
        }
    };

    // kh0: prev-tile global stores (reads Ow + Hn[prevpar] from LDS, stores)
    auto PSTORE = [&](int pr0, int prevpar) {
        const char* Hp = (const char*)Hn[prevpar];
        f16x4 hv4 = *(const f16x4*)(Hp + ((hrow * 256 + hch * 8) ^ ((hrow & 7) << 4)));
        *(f16x4*)(hh_next + ((size_t)(pr0 + hrow) << 7) + hch * 4) = hv4;
#pragma unroll
        for (int j = 0; j < 2; j++) {
            int chunk = (int)threadIdx.x + j * 512;  // 0..1023
            int w = chunk >> 6, r = (chunk >> 2) & 15, c8 = chunk & 3;
            f16x8 tv = *(const f16x8*)&Ow[w][r * OSTR + c8 * 8];
            *(f16x8*)(t_out + ((size_t)(w & 3) * N + (pr0 + r)) * DF
                      + (w >> 2) * 32 + c8 * 8) = tv;
        }
    };

    STAGE(0);
    STAGE(1);
    asm volatile("s_waitcnt vmcnt(1)" ::: "memory");
    __builtin_amdgcn_s_barrier();
    __builtin_amdgcn_sched_barrier(0);

    int it = 0;
    int prev_r0 = -1;
    for (int tile = blockIdx.x; tile < GRU_TILES; tile += GRU_BLOCKS, ++it) {
        const int r0 = tile * 16;
        STAGE(it + 2);                               // 2-deep prefetch into ring slot

        const char* As = (const char*)Ast[it & 3];

        f16x8 A[4];                                  // own K-half: kh0=ah, kh1=hh
#pragma unroll
        for (int kt = 0; kt < 4; kt++) {
            int off = (kh << 12) + ((abase + kt * 64) ^ axor);
            A[kt] = *(const f16x8*)(As + off);
        }

        f32x4 ar = {0.f, 0.f, 0.f, 0.f}, az = {0.f, 0.f, 0.f, 0.f};
        f32x4 an = {0.f, 0.f, 0.f, 0.f};             // kh0: i_n partial; kh1: h_n
#pragma unroll
        for (int kt = 0; kt < 4; kt++) {
            ar = __builtin_amdgcn_mfma_f32_16x16x32_f16(A[kt], br[kt], ar, 0, 0, 0);
            az = __builtin_amdgcn_mfma_f32_16x16x32_f16(A[kt], bz[kt], az, 0, 0, 0);
            an = __builtin_amdgcn_mfma_f32_16x16x32_f16(A[kt], bn[kt], an, 0, 0, 0);
        }

        if (kh == 0) {                               // publish K-half-0 partials
#pragma unroll
            for (int i = 0; i < 4; i++) {
                int row = quad * 4 + i;
                Xp[cg][0][row * XPSTR + col16] = ar[i];
                Xp[cg][1][row * XPSTR + col16] = az[i];
                Xp[cg][2][row * XPSTR + col16] = an[i];
            }
        }
        asm volatile("s_waitcnt lgkmcnt(0)" ::: "memory");   // B1: Xp visible
        __builtin_amdgcn_s_barrier();
        __builtin_amdgcn_sched_barrier(0);

        if (kh == 1) {
            // combine + in-register epilogue + Hn write (16 cols x 16 rows)
            char* Hb = Hn[it & 1];
#pragma unroll
            for (int i = 0; i < 4; i++) {
                int row = quad * 4 + i;
                float pr = Xp[cg][0][row * XPSTR + col16];
                float pz = Xp[cg][1][row * XPSTR + col16];
                float pn = Xp[cg][2][row * XPSTR + col16];  // i_n (full, from kh0)
                float hprev = (float)*(const _Float16*)(
                    As + 4096 + ((row * 256 + c * 2) ^ ((row & 7) << 4)));
                float r = sigmoid_fast(pr + ar[i] + bir);
                float z = sigmoid_fast(pz + az[i] + biz);
                float nn = tanh_fast(pn + bin_ + r * (an[i] + bhn_));
                float hv = (1.f - z) * nn + z * hprev;
                if (out_f32) {
                    out_f32[((size_t)(r0 + row) << 7) + c] = hv;
                } else {
                    *(_Float16*)(Hb + ((row * 256 + c * 2) ^ ((row & 7) << 4))) = (_Float16)hv;
                }
            }
        } else if (t_out && prev_r0 >= 0) {
            PSTORE(prev_r0, (it & 1) ^ 1);           // overlapped with kh1 epilogue
        }

        if (t_out) {
            asm volatile("s_waitcnt lgkmcnt(0)" ::: "memory");   // B2: Hn visible
            __builtin_amdgcn_s_barrier();
            __builtin_amdgcn_sched_barrier(0);

            // lin: all 16 waves, K=128 over Hn, 8 MFMAs
            const char* Hb = (const char*)Hn[it & 1];
            f16x8 A2[4];
#pragma unroll
            for (int kt = 0; kt < 4; kt++) {
                int off = (col16 * 256 + kt * 64 + quad * 16) ^ ((col16 & 7) << 4);
                A2[kt] = *(const f16x8*)(Hb + off);
            }
#pragma unroll
            for (int ct = 0; ct < 2; ct++) {
                f32x4 acc = {0.f, 0.f, 0.f, 0.f};
#pragma unroll
                for (int kt = 0; kt < 4; kt++)
                    acc = __builtin_amdgcn_mfma_f32_16x16x32_f16(A2[kt], wl[ct][kt], acc, 0, 0, 0);
#pragma unroll
                for (int i = 0; i < 4; i++)
                    Ow[wave][(quad * 4 + i) * OSTR + ct * 16 + col16] =
                        (_Float16)(acc[i] + blv[ct]);
            }
            // bottom: vmcnt(4) = allow [stage(it+2), st x3]; guarantees
            // stage(it+1) + prior stores done (in-order). Never 0 in loop.
            asm volatile("s_waitcnt vmcnt(4) lgkmcnt(0)" ::: "memory");
            __builtin_amdgcn_s_barrier();
            __builtin_amdgcn_sched_barrier(0);
        } else {
            asm volatile("s_waitcnt vmcnt(1) lgkmcnt(0)" ::: "memory");
            __builtin_amdgcn_s_barrier();
            __builtin_amdgcn_sched_barrier(0);
        }
        prev_r0 = r0;
    }
    // final tile's deferred stores (its Ow/Hn completed at the last barrier)
    if (t_out && prev_r0 >= 0 && kh == 0) {
        PSTORE(prev_r0, (it & 1) ^ 1);
    }
    asm volatile("s_waitcnt vmcnt(0)" ::: "memory");
}

// ---------------- launch ----------------

extern "C" void kernel_launch(void* const* d_in, const int* in_sizes, int n_in,
                              void* d_out, int out_size, void* d_ws, size_t ws_size,
                              hipStream_t stream) {
    const float* h0    = (const float*)d_in[0];
    const int*   src   = (const int*)d_in[1];
    const int*   dst   = (const int*)d_in[2];
    const int*   ety   = (const int*)d_in[3];
    const float* W_lin = (const float*)d_in[4];
    const float* b_lin = (const float*)d_in[5];
    const float* w_ih  = (const float*)d_in[6];
    const float* w_hh  = (const float*)d_in[7];
    const float* b_ih  = (const float*)d_in[8];
    const float* b_hh  = (const float*)d_in[9];
    float* hout = (float*)d_out;

    char* p = (char*)d_ws;
    auto alloc = [&](size_t bytes) -> char* {
        char* r = p;
        p += (bytes + 255) & ~(size_t)255;
        return r;
    };
    _Float16* h_a    = (_Float16*)alloc((size_t)N_NODES * DF * 2);
    _Float16* h_b    = (_Float16*)alloc((size_t)N_NODES * DF * 2);
    _Float16* a_half = (_Float16*)alloc((size_t)N_NODES * DF * 2);
    _Float16* t_half = (_Float16*)alloc((size_t)N_ETYPES * N_NODES * DF * 2);
    _Float16* Wl_h   = (_Float16*)alloc((size_t)N_ETYPES * DF * DF * 2);
    _Float16* Bc     = (_Float16*)alloc((size_t)3 * DF * 2 * DF * 2);   // [384][256] f16
    int* deg       = (int*)alloc((size_t)N_NODES * 4);
    int* row_start = (int*)alloc((size_t)(N_NODES + 1) * 4);
    int* cursor    = (int*)alloc((size_t)N_NODES * 4);
    int* csr       = (int*)alloc((size_t)N_EDGES * 4);
    int* part      = (int*)alloc((size_t)SCAN_NB * 4);

    hipMemsetAsync(deg, 0, (size_t)N_NODES * 4, stream);
    k_setup<<<(N_NODES * DF / 4 + 255) / 256, 256, 0, stream>>>(
        W_lin, w_ih, w_hh, h0, dst, Wl_h, Bc, h_a, deg);
    k_part<<<SCAN_NB, 256, 0, stream>>>(deg, part, N_NODES);
    k_scan1<<<1, 256, 0, stream>>>(part, SCAN_NB);
    k_row<<<SCAN_NB, 256, 0, stream>>>(deg, part, row_start, cursor, N_NODES);
    k_fill<<<FILL_CHUNKS * 8, 256, 0, stream>>>(src, dst, ety, cursor, csr, N_EDGES);

    _Float16* hc = h_a;
    _Float16* hn = h_b;
    k_lin<<<LIN_BLOCKS, 1024, 0, stream>>>(hc, Wl_h, b_lin, t_half, N_NODES);
    for (int s = 0; s < N_STEPS; s++) {
        k_agg<<<N_NODES / 4, 256, 0, stream>>>(t_half, row_start, csr, a_half, N_NODES);
        const bool last = (s == N_STEPS - 1);
        k_grulin<<<GRU_BLOCKS, 1024, 0, stream>>>(
            a_half, hc, Bc, b_ih, b_hh, Wl_h, b_lin, hn,
            last ? nullptr : t_half, last ? hout : nullptr, N_NODES);
        _Float16* tmp = hc; hc = hn; hn = tmp;
    }
}

// Round 12
// 512.897 us; speedup vs baseline: 1.0754x; 1.0754x over previous
//
#include <hip/hip_runtime.h>
#include <hip/hip_bf16.h>
#include <cstdint>
#include <cstddef>

#define N_NODES 50000
#define N_EDGES 600000
#define DF 128
#define N_ETYPES 4
#define N_STEPS 5
#define SCAN_NB 196        // ceil(50000/256)
#define GRU_TILES 3125     // 50000/16 exact
#define GRU_BLOCKS 256     // 1 block/CU
#define LIN_BLOCKS 256     // k_lin (step-0 only)
#define TSTRIDE 136        // k_lin LDS out-tile row stride (f16)
#define OSTR 76            // k_grulin Ow row stride (f16)
#define FILL_CHUNKS 2344   // ceil(600000/256)
#define FILL_RANGE (N_NODES / 8)   // 6250 nodes per XCD range

typedef _Float16 f16x8 __attribute__((ext_vector_type(8)));
typedef _Float16 f16x4 __attribute__((ext_vector_type(4)));
typedef float f32x4 __attribute__((ext_vector_type(4)));

__device__ __forceinline__ float sigmoid_fast(float x) {
    return 1.0f / (1.0f + __expf(-x));
}
__device__ __forceinline__ float tanh_fast(float x) {
    return 1.0f - 2.0f / (__expf(2.0f * x) + 1.0f);
}

// ---------------- setup kernels (once per launch) ----------------

__global__ __launch_bounds__(256) void k_setup(
    const float* __restrict__ Wl, const float* __restrict__ wih,
    const float* __restrict__ whh, const float* __restrict__ h,
    const int* __restrict__ dst,
    _Float16* __restrict__ Wl_h, _Float16* __restrict__ Bc,
    _Float16* __restrict__ hh, int* __restrict__ deg) {
    int i = blockIdx.x * 256 + threadIdx.x;
    if (i < N_ETYPES * DF * DF * 3 / 2) {            // 98304: Bc (+ Wl_h for i<65536)
        if (i < N_ETYPES * DF * DF) Wl_h[i] = (_Float16)Wl[i];
        int row = i >> 8;                            // 0..383 = g*128 + c
        int k = i & 255;
        float v = (k < 128) ? wih[row * 128 + k] : whh[row * 128 + (k - 128)];
        Bc[i] = (_Float16)v;
    }
    if (i < N_NODES * DF / 4) {                      // 1.6M float4 chunks
        float4 v = ((const float4*)h)[i];
        f16x4 o;
        o.x = (_Float16)v.x; o.y = (_Float16)v.y;
        o.z = (_Float16)v.z; o.w = (_Float16)v.w;
        ((f16x4*)hh)[i] = o;
    }
    if (i < N_EDGES) atomicAdd(&deg[dst[i]], 1);
}

__global__ __launch_bounds__(256) void k_part(
    const int* __restrict__ deg, int* __restrict__ part, int N) {
    __shared__ int s[256];
    int t = threadIdx.x, i = blockIdx.x * 256 + t;
    s[t] = (i < N) ? deg[i] : 0;
    __syncthreads();
    for (int off = 128; off > 0; off >>= 1) {
        if (t < off) s[t] += s[t + off];
        __syncthreads();
    }
    if (t == 0) part[blockIdx.x] = s[0];
}

__global__ __launch_bounds__(256) void k_scan1(int* __restrict__ part, int nb) {
    __shared__ int s[256];
    int t = threadIdx.x;
    int v = (t < nb) ? part[t] : 0;
    s[t] = v;
    __syncthreads();
    for (int off = 1; off < 256; off <<= 1) {
        int u = (t >= off) ? s[t - off] : 0;
        __syncthreads();
        s[t] += u;
        __syncthreads();
    }
    if (t < nb) part[t] = s[t] - v;
}

__global__ __launch_bounds__(256) void k_row(
    const int* __restrict__ deg, const int* __restrict__ part,
    int* __restrict__ row_start, int* __restrict__ cursor, int N) {
    __shared__ int s[256];
    int t = threadIdx.x, i = blockIdx.x * 256 + t;
    int d = (i < N) ? deg[i] : 0;
    s[t] = d;
    __syncthreads();
    for (int off = 1; off < 256; off <<= 1) {
        int u = (t >= off) ? s[t - off] : 0;
        __syncthreads();
        s[t] += u;
        __syncthreads();
    }
    int rs = part[blockIdx.x] + s[t] - d;
    if (i < N) {
        row_start[i] = rs;
        cursor[i] = rs;
        if (i == N - 1) row_start[N] = rs + d;
    }
}

// XCD-partitioned CSR scatter (R5 verified win).
__global__ __launch_bounds__(256) void k_fill(
    const int* __restrict__ src, const int* __restrict__ dst,
    const int* __restrict__ ety, int* __restrict__ cursor,
    int* __restrict__ csr, int E) {
    const int range = blockIdx.x & 7;
    const int chunk = blockIdx.x >> 3;
    const int e = chunk * 256 + threadIdx.x;
    const int lo = range * FILL_RANGE;
    const int hi = lo + FILL_RANGE;
    if (e < E) {
        int d = dst[e];
        if (d >= lo && d < hi) {
            int slot = atomicAdd(&cursor[d], 1);
            csr[slot] = src[e] | ((ety[e] - 1) << 16);   // src < 65536, et in 0..3
        }
    }
}

// ---------------- per-step kernels ----------------

// t_0 only (R4 verified)
__global__ __launch_bounds__(1024) void k_lin(
    const _Float16* __restrict__ hh, const _Float16* __restrict__ Wl,
    const float* __restrict__ b_lin, _Float16* __restrict__ t_out, int N) {
    __shared__ _Float16 O[2][N_ETYPES * 16 * TSTRIDE];
    __shared__ __align__(16) char Ast[4][4096];
    const int wave = threadIdx.x >> 6, lane = threadIdx.x & 63;
    const int col16 = lane & 15, quad = lane >> 4;
    const int g = wave >> 2;
    const int s = wave & 3;

    f16x8 b[2][4];
#pragma unroll
    for (int ct = 0; ct < 2; ct++) {
        const _Float16* bp = Wl + (size_t)g * DF * DF
                           + (size_t)(s * 32 + ct * 16 + col16) * DF + quad * 8;
#pragma unroll
        for (int kt = 0; kt < 4; kt++) b[ct][kt] = *(const f16x8*)(bp + kt * 32);
    }
    const float bias0 = b_lin[g * DF + s * 32 + col16];
    const float bias1 = b_lin[g * DF + s * 32 + 16 + col16];

    const int olocal = (wave & 3) * 1024 + lane * 16;
    const int oswl = olocal ^ (((olocal >> 8) & 7) << 4);
    const int abase = col16 * 256 + quad * 16;
    const int axor = (col16 & 7) << 4;

    auto STAGE = [&](int iter) {
        if (wave < 4) {
            int tt = blockIdx.x + iter * LIN_BLOCKS;
            if (tt >= GRU_TILES) tt = GRU_TILES - 1;
            const char* gp = (const char*)hh + (size_t)tt * 4096 + oswl;
            char* lp = &Ast[iter & 3][(wave & 3) * 1024];
            __builtin_amdgcn_global_load_lds(
                (const __attribute__((address_space(1))) void*)gp,
                (__attribute__((address_space(3))) void*)lp, 16, 0, 0);
        }
    };

    const int ek = threadIdx.x >> 8;
    const int erow = (threadIdx.x & 255) >> 4;
    const int ec8 = threadIdx.x & 15;

    STAGE(0);
    STAGE(1);
    asm volatile("s_waitcnt vmcnt(1)" ::: "memory");
    __builtin_amdgcn_s_barrier();
    __builtin_amdgcn_sched_barrier(0);

    int it = 0;
    for (int tile = blockIdx.x; tile < GRU_TILES; tile += LIN_BLOCKS, ++it) {
        const int r0 = tile * 16;
        STAGE(it + 2);

        const char* As = (const char*)Ast[it & 3];
        _Float16* Ob = O[it & 1];

        f16x8 A[4];
#pragma unroll
        for (int kt = 0; kt < 4; kt++) {
            int off = (abase + kt * 64) ^ axor;
            A[kt] = *(const f16x8*)(As + off);
        }

        f32x4 acc0 = {0.f, 0.f, 0.f, 0.f}, acc1 = {0.f, 0.f, 0.f, 0.f};
#pragma unroll
        for (int kt = 0; kt < 4; kt++) {
            acc0 = __builtin_amdgcn_mfma_f32_16x16x32_f16(A[kt], b[0][kt], acc0, 0, 0, 0);
            acc1 = __builtin_amdgcn_mfma_f32_16x16x32_f16(A[kt], b[1][kt], acc1, 0, 0, 0);
        }

        _Float16* Og = Ob + g * (16 * TSTRIDE);
#pragma unroll
        for (int i = 0; i < 4; i++) {
            Og[(quad * 4 + i) * TSTRIDE + s * 32 + col16] = (_Float16)(acc0[i] + bias0);
            Og[(quad * 4 + i) * TSTRIDE + s * 32 + 16 + col16] = (_Float16)(acc1[i] + bias1);
        }

        asm volatile("s_waitcnt vmcnt(1) lgkmcnt(0)" ::: "memory");
        __builtin_amdgcn_s_barrier();
        __builtin_amdgcn_sched_barrier(0);

        f16x8 v = *(const f16x8*)&Ob[ek * (16 * TSTRIDE) + erow * TSTRIDE + ec8 * 8];
        *(f16x8*)(t_out + ((size_t)ek * N + (r0 + erow)) * DF + ec8 * 8) = v;
    }
    asm volatile("s_waitcnt vmcnt(0)" ::: "memory");
}

// a[n][:] = sum over incoming edges of t[et][src][:] (verified; at the random
// 256B-gather delivered-bytes wall ~4TB/s from L3)
__global__ __launch_bounds__(256) void k_agg(
    const _Float16* __restrict__ t, const int* __restrict__ row_start,
    const int* __restrict__ csr, _Float16* __restrict__ ah, int N) {
    const int wave = threadIdx.x >> 6, lane = threadIdx.x & 63;
    const int g4 = lane >> 4;
    const int c8 = lane & 15;
    const int n = blockIdx.x * 4 + wave;
    const int beg = row_start[n], end = row_start[n + 1];
    float acc[8] = {0.f, 0.f, 0.f, 0.f, 0.f, 0.f, 0.f, 0.f};
    for (int e = beg; e < end; e += 16) {
        int i0 = e + g4, i1 = e + 4 + g4, i2 = e + 8 + g4, i3 = e + 12 + g4;
        float m0 = (i0 < end) ? 1.0f : 0.0f;
        float m1 = (i1 < end) ? 1.0f : 0.0f;
        float m2 = (i2 < end) ? 1.0f : 0.0f;
        float m3 = (i3 < end) ? 1.0f : 0.0f;
        int j0 = (i0 < end) ? i0 : end - 1;
        int j1 = (i1 < end) ? i1 : end - 1;
        int j2 = (i2 < end) ? i2 : end - 1;
        int j3 = (i3 < end) ? i3 : end - 1;
        int p0 = csr[j0], p1 = csr[j1], p2 = csr[j2], p3 = csr[j3];
        f16x8 x0 = *(const f16x8*)(t + ((((size_t)(p0 >> 16)) * N + (p0 & 0xFFFF)) << 7) + c8 * 8);
        f16x8 x1 = *(const f16x8*)(t + ((((size_t)(p1 >> 16)) * N + (p1 & 0xFFFF)) << 7) + c8 * 8);
        f16x8 x2 = *(const f16x8*)(t + ((((size_t)(p2 >> 16)) * N + (p2 & 0xFFFF)) << 7) + c8 * 8);
        f16x8 x3 = *(const f16x8*)(t + ((((size_t)(p3 >> 16)) * N + (p3 & 0xFFFF)) << 7) + c8 * 8);
#pragma unroll
        for (int j = 0; j < 8; j++) acc[j] += m0 * (float)x0[j];
#pragma unroll
        for (int j = 0; j < 8; j++) acc[j] += m1 * (float)x1[j];
#pragma unroll
        for (int j = 0; j < 8; j++) acc[j] += m2 * (float)x2[j];
#pragma unroll
        for (int j = 0; j < 8; j++) acc[j] += m3 * (float)x3[j];
    }
#pragma unroll
    for (int j = 0; j < 8; j++) {
        acc[j] += __shfl_xor(acc[j], 32, 64);
        acc[j] += __shfl_xor(acc[j], 16, 64);
    }
    if (lane < 16) {
        f16x8 o;
#pragma unroll
        for (int j = 0; j < 8; j++) o[j] = (_Float16)acc[j];
        *(f16x8*)(ah + ((size_t)n << 7) + c8 * 8) = o;
    }
}

// FUSED GRU + next-step linear, PAIRED + DEEP-PREFETCH (R12). R10's pairing
// kept, but its bottom vmcnt(0) drain (which canceled the pairing gain) is
// replaced by the verified never-drain discipline: 8-slot Ast ring, pairs
// prefetched TWO ahead (iteration j issues STAGE(2j+4),(2j+5)), so the bottom
// wait only needs stage(2j+2),(2j+3) -- issued a full pair earlier. Per-wave
// in-order vmcnt accounting at the bottom wait: ops newer than stage(2j+3) =
// 6 stores(j-1) + 2 stages(j) = 8 -> vmcnt(8) (t-steps); last step has 8
// out_f32 stores/pair inside GRUC -> 18 -> vmcnt(18). vmcnt(0) only in the
// once-per-kernel leftover prologue. Zero registers live across barriers.
__global__ __launch_bounds__(512, 2) void k_grulin(
    const _Float16* __restrict__ ah, const _Float16* __restrict__ hh,
    const _Float16* __restrict__ Bc, const float* __restrict__ b_ih,
    const float* __restrict__ b_hh, const _Float16* __restrict__ Wl,
    const float* __restrict__ b_lin, _Float16* __restrict__ hh_next,
    _Float16* __restrict__ t_out, float* __restrict__ out_f32, int N) {
    __shared__ __align__(16) char Ast[8][8192];      // A-tile ring: [slot][ah 4KB | hh 4KB]
    __shared__ __align__(16) char Hn[2][2][4096];    // h_next tiles: [pair parity][tile-in-pair]
    __shared__ _Float16 Ow[8][2][16 * OSTR];         // per-wave t transpose, per tile-in-pair
    const int wave = threadIdx.x >> 6, lane = threadIdx.x & 63;
    const int col16 = lane & 15, quad = lane >> 4;
    const int c = wave * 16 + col16;                 // gru output col 0..127

    // gru persistent B frags (R7 verified)
    f16x8 br[8], bz[8], bi[4], bh[4];
    {
        const _Float16* Br = Bc + ((size_t)c << 8);
        const _Float16* Bz = Bc + ((size_t)(128 + c) << 8);
        const _Float16* Bn = Bc + ((size_t)(256 + c) << 8);
#pragma unroll
        for (int kt = 0; kt < 8; kt++) {
            br[kt] = *(const f16x8*)(Br + kt * 32 + quad * 8);
            bz[kt] = *(const f16x8*)(Bz + kt * 32 + quad * 8);
        }
#pragma unroll
        for (int kt = 0; kt < 4; kt++) {
            bi[kt] = *(const f16x8*)(Bn + kt * 32 + quad * 8);
            bh[kt] = *(const f16x8*)(Bn + 128 + kt * 32 + quad * 8);
        }
    }
    const float bir = b_ih[c] + b_hh[c];
    const float biz = b_ih[128 + c] + b_hh[128 + c];
    const float bin_ = b_ih[256 + c];
    const float bhn_ = b_hh[256 + c];

    // lin persistent W frags: wave -> (etype = wave>>1, 64-col half = wave&1)
    const int et = wave >> 1;
    const int ch64 = (wave & 1) * 64;
    f16x8 wl[4][4];
    float blv[4];
#pragma unroll
    for (int ct = 0; ct < 4; ct++) {
        const _Float16* wp = Wl + (size_t)et * DF * DF
                           + (size_t)(ch64 + ct * 16 + col16) * DF + quad * 8;
#pragma unroll
        for (int kt = 0; kt < 4; kt++) wl[ct][kt] = *(const f16x8*)(wp + kt * 32);
        blv[ct] = b_lin[et * DF + ch64 + ct * 16 + col16];
    }

    const int olocal = (wave & 3) * 1024 + lane * 16;
    const int oswl = olocal ^ (((olocal >> 8) & 7) << 4);
    const char* sbase = (wave < 4) ? (const char*)ah : (const char*)hh;
    const int abase = col16 * 256 + quad * 16;
    const int axor = (col16 & 7) << 4;

    // store lanes (fixed per thread)
    const int hrow = threadIdx.x >> 5, hch = threadIdx.x & 31;  // h_next: 16x32 f16x4 chunks
    const int trow0 = lane >> 3, tc80 = lane & 7;               // t chunk j=0 (rows 0-7)
    const int trow1 = 8 + (lane >> 3), tc81 = lane & 7;         // t chunk j=1 (rows 8-15)

    auto STAGE = [&](int tidx) {
        int tt = blockIdx.x + tidx * GRU_BLOCKS;
        if (tt >= GRU_TILES) tt = GRU_TILES - 1;     // clamp keeps vmcnt accounting uniform
        const char* gp = sbase + (size_t)tt * 4096 + oswl;
        char* lp = &Ast[tidx & 7][wave * 1024];
        __builtin_amdgcn_global_load_lds(
            (const __attribute__((address_space(1))) void*)gp,
            (__attribute__((address_space(3))) void*)lp, 16, 0, 0);
    };

    auto GRUC = [&](int tidx, char* Hb) {
        const int r0 = (blockIdx.x + tidx * GRU_BLOCKS) * 16;
        const char* As = (const char*)Ast[tidx & 7];
        f16x8 A[8];                                  // kt<4 = ah part, kt>=4 = hh part
#pragma unroll
        for (int kt = 0; kt < 8; kt++) {
            int off = ((kt & 4) << 10) + abase + (kt & 3) * 64;
            off ^= axor;
            A[kt] = *(const f16x8*)(As + off);
        }
        f32x4 ar = {0.f, 0.f, 0.f, 0.f}, az = {0.f, 0.f, 0.f, 0.f};
        f32x4 ai = {0.f, 0.f, 0.f, 0.f}, an = {0.f, 0.f, 0.f, 0.f};
#pragma unroll
        for (int kt = 0; kt < 8; kt++) {
            ar = __builtin_amdgcn_mfma_f32_16x16x32_f16(A[kt], br[kt], ar, 0, 0, 0);
            az = __builtin_amdgcn_mfma_f32_16x16x32_f16(A[kt], bz[kt], az, 0, 0, 0);
        }
#pragma unroll
        for (int kt = 0; kt < 4; kt++) {
            ai = __builtin_amdgcn_mfma_f32_16x16x32_f16(A[kt], bi[kt], ai, 0, 0, 0);
            an = __builtin_amdgcn_mfma_f32_16x16x32_f16(A[4 + kt], bh[kt], an, 0, 0, 0);
        }
#pragma unroll
        for (int i = 0; i < 4; i++) {
            int row = quad * 4 + i;
            int hoff = (4096 + row * 256 + c * 2) ^ ((row & 7) << 4);
            float hprev = (float)*(const _Float16*)(As + hoff);
            float r = sigmoid_fast(ar[i] + bir);
            float z = sigmoid_fast(az[i] + biz);
            float nn = tanh_fast(ai[i] + bin_ + r * (an[i] + bhn_));
            float hv = (1.f - z) * nn + z * hprev;
            if (out_f32) {
                out_f32[((size_t)(r0 + row) << 7) + c] = hv;
            } else {
                *(_Float16*)(Hb + ((row * 256 + c * 2) ^ ((row & 7) << 4))) = (_Float16)hv;
            }
        }
    };

    auto LINC = [&](const char* Hp, _Float16* Owb) {
        f16x8 A2[4];
#pragma unroll
        for (int kt = 0; kt < 4; kt++) {
            int off = (col16 * 256 + kt * 64 + quad * 16) ^ ((col16 & 7) << 4);
            A2[kt] = *(const f16x8*)(Hp + off);
        }
#pragma unroll
        for (int ct = 0; ct < 4; ct++) {
            f32x4 acc = {0.f, 0.f, 0.f, 0.f};
#pragma unroll
            for (int kt = 0; kt < 4; kt++)
                acc = __builtin_amdgcn_mfma_f32_16x16x32_f16(A2[kt], wl[ct][kt], acc, 0, 0, 0);
#pragma unroll
            for (int i = 0; i < 4; i++)
                Owb[(quad * 4 + i) * OSTR + ct * 16 + col16] = (_Float16)(acc[i] + blv[ct]);
        }
    };

    auto OSTORE = [&](int tidx, const char* Hp, const _Float16* Owb) {
        const int r0 = (blockIdx.x + tidx * GRU_BLOCKS) * 16;
        f16x8 tv0 = *(const f16x8*)&Owb[trow0 * OSTR + tc80 * 8];
        f16x8 tv1 = *(const f16x8*)&Owb[trow1 * OSTR + tc81 * 8];
        f16x4 hv4 = *(const f16x4*)(Hp + ((hrow * 256 + hch * 8) ^ ((hrow & 7) << 4)));
        *(f16x8*)(t_out + ((size_t)et * N + (r0 + trow0)) * DF + ch64 + tc80 * 8) = tv0;
        *(f16x8*)(t_out + ((size_t)et * N + (r0 + trow1)) * DF + ch64 + tc81 * 8) = tv1;
        *(f16x4*)(hh_next + ((size_t)(r0 + hrow) << 7) + hch * 4) = hv4;
    };

    // prologue: stage pairs 0 and 1 (tiles 0..3); wait for pair 0 only
    STAGE(0);
    STAGE(1);
    STAGE(2);
    STAGE(3);
    asm volatile("s_waitcnt vmcnt(2)" ::: "memory");
    __builtin_amdgcn_s_barrier();
    __builtin_amdgcn_sched_barrier(0);

    for (int j = 0; j < 6; ++j) {                    // exactly 6 full pairs per block
        STAGE(2 * j + 4);                            // 2-pair-deep prefetch (clamped at end)
        STAGE(2 * j + 5);
        char* H0 = Hn[j & 1][0];
        char* H1 = Hn[j & 1][1];
        GRUC(2 * j, H0);
        GRUC(2 * j + 1, H1);
        if (t_out) {
            asm volatile("s_waitcnt lgkmcnt(0)" ::: "memory");   // B1: Hn complete
            __builtin_amdgcn_s_barrier();
            __builtin_amdgcn_sched_barrier(0);
            LINC(H0, Ow[wave][0]);
            LINC(H1, Ow[wave][1]);
            // bottom: counted, never drained. Need stage(2j+2),(2j+3) (issued
            // a pair ago) complete; newer ops = 6 stores(j-1) + 2 stages(j).
            asm volatile("s_waitcnt vmcnt(8) lgkmcnt(0)" ::: "memory");
            __builtin_amdgcn_s_barrier();
            __builtin_amdgcn_sched_barrier(0);
            OSTORE(2 * j, H0, Ow[wave][0]);
            OSTORE(2 * j + 1, H1, Ow[wave][1]);
        } else {
            // newer ops = 8 out_f32 stores(j-1) + 2 stages(j) + 8 stores(j).
            asm volatile("s_waitcnt vmcnt(18) lgkmcnt(0)" ::: "memory");
            __builtin_amdgcn_s_barrier();
            __builtin_amdgcn_sched_barrier(0);
        }
    }
    // leftover 13th tile (tidx 12) for blocks bid <= 52; staged at j=4.
    if (blockIdx.x + 12 * GRU_BLOCKS < GRU_TILES) {
        asm volatile("s_waitcnt vmcnt(0) lgkmcnt(0)" ::: "memory");  // once per kernel
        __builtin_amdgcn_s_barrier();
        __builtin_amdgcn_sched_barrier(0);
        char* H0 = Hn[0][0];                         // last pair used parity 1 -> free
        GRUC(12, H0);
        if (t_out) {
            asm volatile("s_waitcnt lgkmcnt(0)" ::: "memory");
            __builtin_amdgcn_s_barrier();
            __builtin_amdgcn_sched_barrier(0);
            LINC(H0, Ow[wave][0]);
            OSTORE(12, H0, Ow[wave][0]);             // no writer follows: safe immediately
        }
    }
    asm volatile("s_waitcnt vmcnt(0)" ::: "memory");
}

// ---------------- launch ----------------

extern "C" void kernel_launch(void* const* d_in, const int* in_sizes, int n_in,
                              void* d_out, int out_size, void* d_ws, size_t ws_size,
                              hipStream_t stream) {
    const float* h0    = (const float*)d_in[0];
    const int*   src   = (const int*)d_in[1];
    const int*   dst   = (const int*)d_in[2];
    const int*   ety   = (const int*)d_in[3];
    const float* W_lin = (const float*)d_in[4];
    const float* b_lin = (const float*)d_in[5];
    const float* w_ih  = (const float*)d_in[6];
    const float* w_hh  = (const float*)d_in[7];
    const float* b_ih  = (const float*)d_in[8];
    const float* b_hh  = (const float*)d_in[9];
    float* hout = (float*)d_out;

    char* p = (char*)d_ws;
    auto alloc = [&](size_t bytes) -> char* {
        char* r = p;
        p += (bytes + 255) & ~(size_t)255;
        return r;
    };
    _Float16* h_a    = (_Float16*)alloc((size_t)N_NODES * DF * 2);
    _Float16* h_b    = (_Float16*)alloc((size_t)N_NODES * DF * 2);
    _Float16* a_half = (_Float16*)alloc((size_t)N_NODES * DF * 2);
    _Float16* t_half = (_Float16*)alloc((size_t)N_ETYPES * N_NODES * DF * 2);
    _Float16* Wl_h   = (_Float16*)alloc((size_t)N_ETYPES * DF * DF * 2);
    _Float16* Bc     = (_Float16*)alloc((size_t)3 * DF * 2 * DF * 2);   // [384][256] f16
    int* deg       = (int*)alloc((size_t)N_NODES * 4);
    int* row_start = (int*)alloc((size_t)(N_NODES + 1) * 4);
    int* cursor    = (int*)alloc((size_t)N_NODES * 4);
    int* csr       = (int*)alloc((size_t)N_EDGES * 4);
    int* part      = (int*)alloc((size_t)SCAN_NB * 4);

    hipMemsetAsync(deg, 0, (size_t)N_NODES * 4, stream);
    k_setup<<<(N_NODES * DF / 4 + 255) / 256, 256, 0, stream>>>(
        W_lin, w_ih, w_hh, h0, dst, Wl_h, Bc, h_a, deg);
    k_part<<<SCAN_NB, 256, 0, stream>>>(deg, part, N_NODES);
    k_scan1<<<1, 256, 0, stream>>>(part, SCAN_NB);
    k_row<<<SCAN_NB, 256, 0, stream>>>(deg, part, row_start, cursor, N_NODES);
    k_fill<<<FILL_CHUNKS * 8, 256, 0, stream>>>(src, dst, ety, cursor, csr, N_EDGES);

    _Float16* hc = h_a;
    _Float16* hn = h_b;
    k_lin<<<LIN_BLOCKS, 1024, 0, stream>>>(hc, Wl_h, b_lin, t_half, N_NODES);
    for (int s = 0; s < N_STEPS; s++) {
        k_agg<<<N_NODES / 4, 256, 0, stream>>>(t_half, row_start, csr, a_half, N_NODES);
        const bool last = (s == N_STEPS - 1);
        k_grulin<<<GRU_BLOCKS, 512, 0, stream>>>(
            a_half, hc, Bc, b_ih, b_hh, Wl_h, b_lin, hn,
            last ? nullptr : t_half, last ? hout : nullptr, N_NODES);
        _Float16* tmp = hc; hc = hn; hn = tmp;
    }
}